// Round 4
// baseline (465.087 us; speedup 1.0000x reference)
//
#include <hip/hip_runtime.h>
#include <hip/hip_bf16.h>

#define Df 64
#define NN 10000
#define EE 160000
#define RR 16
#define CC 512

// ---------------- static device scratch (no d_ws dependency) ----------------
__device__ float g_h0[NN * Df];                       // 2.56 MB
__device__ float g_h1[(size_t)RR * NN * Df];          // 41 MB
__device__ float g_h2[(size_t)RR * NN * Df];          // 41 MB
__device__ int g_cnt[NN], g_row[NN + 1], g_pos[NN];
__device__ int g_csr[EE];
__device__ float g_score[RR * CC];

// ---------------- zero histogram ----------------
__global__ void k_zero() {
    int i = blockIdx.x * 256 + threadIdx.x;
    if (i < NN) g_cnt[i] = 0;
}

// ---------------- h0 = coords @ W_emb + b_emb ----------------
__global__ void k_h0(const float* __restrict__ coords, const float* __restrict__ We,
                     const float* __restrict__ be) {
    int i = blockIdx.x * 256 + threadIdx.x;
    if (i >= NN * Df) return;
    int n = i >> 6, d = i & 63;
    g_h0[i] = coords[2 * n] * We[d] + coords[2 * n + 1] * We[Df + d] + be[d];
}

// ---------------- CSR build ----------------
__global__ void k_hist(const int* __restrict__ dst) {
    int e = blockIdx.x * 256 + threadIdx.x;
    if (e < EE) atomicAdd(&g_cnt[dst[e]], 1);
}

__global__ void k_scan() {
    __shared__ int sums[1024];
    int t = threadIdx.x;                       // 1024 threads
    const int PER = (NN + 1023) / 1024;        // 10
    int base = t * PER;
    int loc = 0;
    for (int k = 0; k < PER; k++) { int v = base + k; if (v < NN) loc += g_cnt[v]; }
    sums[t] = loc;
    __syncthreads();
    for (int off = 1; off < 1024; off <<= 1) {
        int x = (t >= off) ? sums[t - off] : 0;
        __syncthreads();
        sums[t] += x;
        __syncthreads();
    }
    int run = (t > 0) ? sums[t - 1] : 0;
    for (int k = 0; k < PER; k++) {
        int v = base + k;
        if (v < NN) { g_row[v] = run; g_pos[v] = run; run += g_cnt[v]; }
    }
    if (t == 1023) g_row[NN] = sums[1023];
}

__global__ void k_fill(const int* __restrict__ src, const int* __restrict__ dst) {
    int e = blockIdx.x * 256 + threadIdx.x;
    if (e < EE) {
        int p = atomicAdd(&g_pos[dst[e]], 1);
        g_csr[p] = src[e];
    }
}

// ---------------- fused GNN layer ----------------
// grid (NN, RR), block 64. layer 0: g_h0 -> g_h1; layer 1: g_h1 -> g_h2.
__global__ void k_layer(const int* __restrict__ removal_idx, int layer,
                        const float* __restrict__ Ws, const float* __restrict__ Wn,
                        const float* __restrict__ b) {
    int v = blockIdx.x;
    int ri = blockIdx.y;
    int r = removal_idx[ri];
    int d = threadIdx.x;

    const float* hin = layer ? (g_h1 + (size_t)ri * NN * Df) : g_h0;
    float* hout      = (layer ? g_h2 : g_h1) + (size_t)ri * NN * Df;

    float aggd = 0.f; int cnt = 0;
    if (v != r) {
        int s0 = g_row[v], s1 = g_row[v + 1];
        for (int i = s0; i < s1; i++) {
            int s = g_csr[i];
            if (s == r) continue;               // masked edge (src removed)
            aggd += hin[s * Df + d];
            cnt++;
        }
    }
    float aggn = aggd / fmaxf((float)cnt, 1.f);

    __shared__ float hv_s[Df], ag_s[Df];
    float hv = hin[v * Df + d];
    hv_s[d] = hv; ag_s[d] = aggn;
    __syncthreads();

    float acc = b[d];
#pragma unroll 16
    for (int k = 0; k < Df; k++)
        acc += hv_s[k] * Ws[k * Df + d] + ag_s[k] * Wn[k * Df + d];

    hout[v * Df + d] = fmaxf(acc, 0.f) + hv;
}

// ---------------- edge scoring ----------------
__global__ void k_score(const int* __restrict__ conn, const int* __restrict__ removal_idx,
                        const int* __restrict__ esrc, const int* __restrict__ edst,
                        const float* __restrict__ We, const float* __restrict__ be,
                        const float* __restrict__ Wsc, const float* __restrict__ bsc) {
    int c = blockIdx.x, ri = blockIdx.y;
    int r = removal_idx[ri];
    int e = conn[ri * CC + c];
    int s = esrc[e], dd = edst[e];
    int j = threadIdx.x;

    __shared__ float hs[Df], hd[Df];
    const float* h2r = g_h2 + (size_t)ri * NN * Df;
    hs[j] = h2r[s * Df + j];
    hd[j] = h2r[dd * Df + j];
    __syncthreads();

    float acc = be[j];
#pragma unroll 16
    for (int k = 0; k < Df; k++)
        acc += hs[k] * We[k * Df + j] + hd[k] * We[(Df + k) * Df + j];
    float ef = fmaxf(acc, 0.f);

    float part = ef * Wsc[Df + j] + g_h0[r * Df + j] * Wsc[j];
#pragma unroll
    for (int off = 32; off > 0; off >>= 1) part += __shfl_xor(part, off);
    if (j == 0) g_score[ri * CC + c] = part + bsc[0];
}

// ---------------- softmax over C per removal ----------------
__global__ void k_softmax(float* __restrict__ out) {
    int r = blockIdx.x;
    int t = threadIdx.x;                        // 256 threads, 2 elems each
    float v0 = g_score[r * CC + t];
    float v1 = g_score[r * CC + 256 + t];
    __shared__ float red[256];
    red[t] = fmaxf(v0, v1);
    __syncthreads();
    for (int off = 128; off > 0; off >>= 1) {
        if (t < off) red[t] = fmaxf(red[t], red[t + off]);
        __syncthreads();
    }
    float mx = red[0];
    __syncthreads();
    float e0 = expf(v0 - mx), e1 = expf(v1 - mx);
    red[t] = e0 + e1;
    __syncthreads();
    for (int off = 128; off > 0; off >>= 1) {
        if (t < off) red[t] += red[t + off];
        __syncthreads();
    }
    float inv = 1.f / red[0];
    out[r * CC + t] = e0 * inv;
    out[r * CC + 256 + t] = e1 * inv;
}

extern "C" void kernel_launch(void* const* d_in, const int* in_sizes, int n_in,
                              void* d_out, int out_size, void* d_ws, size_t ws_size,
                              hipStream_t stream) {
    const float* coords   = (const float*)d_in[0];
    const float* W_emb    = (const float*)d_in[1];
    const float* b_emb    = (const float*)d_in[2];
    const float* W_self0  = (const float*)d_in[3];
    const float* W_neigh0 = (const float*)d_in[4];
    const float* b_gnn0   = (const float*)d_in[5];
    const float* W_self1  = (const float*)d_in[6];
    const float* W_neigh1 = (const float*)d_in[7];
    const float* b_gnn1   = (const float*)d_in[8];
    const float* W_edge   = (const float*)d_in[9];
    const float* b_edge   = (const float*)d_in[10];
    const float* W_score  = (const float*)d_in[11];
    const float* b_score  = (const float*)d_in[12];
    const int* esrc       = (const int*)d_in[13];
    const int* edst       = (const int*)d_in[14];
    const int* removal    = (const int*)d_in[15];
    const int* conn       = (const int*)d_in[16];

    k_zero<<<(NN + 255) / 256, 256, 0, stream>>>();
    k_h0<<<(NN * Df + 255) / 256, 256, 0, stream>>>(coords, W_emb, b_emb);
    k_hist<<<(EE + 255) / 256, 256, 0, stream>>>(edst);
    k_scan<<<1, 1024, 0, stream>>>();
    k_fill<<<(EE + 255) / 256, 256, 0, stream>>>(esrc, edst);

    dim3 g1(NN, RR);
    k_layer<<<g1, 64, 0, stream>>>(removal, 0, W_self0, W_neigh0, b_gnn0);
    k_layer<<<g1, 64, 0, stream>>>(removal, 1, W_self1, W_neigh1, b_gnn1);

    dim3 g2(CC, RR);
    k_score<<<g2, 64, 0, stream>>>(conn, removal, esrc, edst,
                                   W_edge, b_edge, W_score, b_score);

    k_softmax<<<RR, 256, 0, stream>>>((float*)d_out);
}

// Round 5
// 169.426 us; speedup vs baseline: 2.7451x; 2.7451x over previous
//
#include <hip/hip_runtime.h>
#include <hip/hip_bf16.h>

#define Df 64
#define NN 10000
#define EE 160000
#define RR 16
#define CC 512
#define CAP1 96
#define CAP2 1536

// ---------------- static device scratch ----------------
__device__ float g_h0[NN * Df];          // init embeddings (shared across removals)
__device__ float g_h1b[NN * Df];         // baseline (no-removal) layer-1 output
__device__ float g_h2b[NN * Df];         // baseline layer-2 output
__device__ int g_cntI[NN], g_rowI[NN + 1], g_posI[NN], g_csrI[EE]; // in-CSR (by dst -> src)
__device__ int g_cntO[NN], g_rowO[NN + 1], g_posO[NN], g_csrO[EE]; // out-CSR (by src -> dst)
__device__ int g_mark1[RR][NN];          // node -> slot+1 in g_d1 (0 = baseline)
__device__ int g_mark2[RR][NN];          // node -> slot+1 in g_d2
__device__ int g_n1[RR], g_n2[RR];
__device__ int g_list1[RR][CAP1];
__device__ int g_list2[RR][CAP2];
__device__ float g_d1[RR][CAP1][Df];
__device__ float g_d2[RR][CAP2][Df];
__device__ float g_score[RR * CC];

// ---------------- zero counters & marks ----------------
__global__ void k_zero() {
    int i = blockIdx.x * 256 + threadIdx.x;     // launched with >= RR*NN threads
    if (i < NN) { g_cntI[i] = 0; g_cntO[i] = 0; }
    if (i < RR * NN) { (&g_mark1[0][0])[i] = 0; (&g_mark2[0][0])[i] = 0; }
    if (i < RR) { g_n1[i] = 0; g_n2[i] = 0; }
}

// ---------------- h0 = coords @ W_emb + b_emb ----------------
__global__ void k_h0(const float* __restrict__ coords, const float* __restrict__ We,
                     const float* __restrict__ be) {
    int i = blockIdx.x * 256 + threadIdx.x;
    if (i >= NN * Df) return;
    int n = i >> 6, d = i & 63;
    g_h0[i] = coords[2 * n] * We[d] + coords[2 * n + 1] * We[Df + d] + be[d];
}

// ---------------- CSR build (both directions) ----------------
__global__ void k_hist(const int* __restrict__ src, const int* __restrict__ dst) {
    int e = blockIdx.x * 256 + threadIdx.x;
    if (e < EE) { atomicAdd(&g_cntI[dst[e]], 1); atomicAdd(&g_cntO[src[e]], 1); }
}

__global__ void k_scan() {
    __shared__ int sums[1024];
    int t = threadIdx.x;                       // 1024 threads
    const int PER = (NN + 1023) / 1024;        // 10
    for (int pass = 0; pass < 2; pass++) {
        const int* cnt = pass ? g_cntO : g_cntI;
        int* row = pass ? g_rowO : g_rowI;
        int* pos = pass ? g_posO : g_posI;
        __syncthreads();
        int base = t * PER;
        int loc = 0;
        for (int k = 0; k < PER; k++) { int v = base + k; if (v < NN) loc += cnt[v]; }
        sums[t] = loc;
        __syncthreads();
        for (int off = 1; off < 1024; off <<= 1) {
            int x = (t >= off) ? sums[t - off] : 0;
            __syncthreads();
            sums[t] += x;
            __syncthreads();
        }
        int run = (t > 0) ? sums[t - 1] : 0;
        for (int k = 0; k < PER; k++) {
            int v = base + k;
            if (v < NN) { row[v] = run; pos[v] = run; run += cnt[v]; }
        }
        if (t == 1023) row[NN] = sums[1023];
    }
}

__global__ void k_fill(const int* __restrict__ src, const int* __restrict__ dst) {
    int e = blockIdx.x * 256 + threadIdx.x;
    if (e < EE) {
        int p = atomicAdd(&g_posI[dst[e]], 1);
        g_csrI[p] = src[e];
        int q = atomicAdd(&g_posO[src[e]], 1);
        g_csrO[q] = dst[e];
    }
}

// ---------------- baseline (unmasked) GNN layer: grid NN, block 64 ----------------
__global__ void k_base(int layer, const float* __restrict__ Ws,
                       const float* __restrict__ Wn, const float* __restrict__ b) {
    int v = blockIdx.x;
    int d = threadIdx.x;
    const float* hin = layer ? g_h1b : g_h0;
    float* hout      = layer ? g_h2b : g_h1b;

    int s0 = g_rowI[v], s1 = g_rowI[v + 1];
    float aggd = 0.f;
    for (int i = s0; i < s1; i++) aggd += hin[g_csrI[i] * Df + d];
    float aggn = aggd / fmaxf((float)(s1 - s0), 1.f);

    __shared__ float hv_s[Df], ag_s[Df];
    float hv = hin[v * Df + d];
    hv_s[d] = hv; ag_s[d] = aggn;
    __syncthreads();

    float acc = b[d];
#pragma unroll 16
    for (int k = 0; k < Df; k++)
        acc += hv_s[k] * Ws[k * Df + d] + ag_s[k] * Wn[k * Df + d];

    hout[v * Df + d] = fmaxf(acc, 0.f) + hv;
}

// ---------------- claim helper ----------------
__device__ inline void claim(int ri, int v, int* mark, int* n, int* list, int cap) {
    int old = atomicCAS(&mark[v], 0, -1);
    if (old == 0) {
        int p = atomicAdd(n, 1);
        if (p < cap) { list[p] = v; atomicExch(&mark[v], p + 1); }
        else atomicExch(&mark[v], 0);           // overflow guard (never expected)
    }
}

// ---------------- A1 = {r} ∪ out-neighbors(r) ----------------
__global__ void k_mark1(const int* __restrict__ removal_idx) {
    int ri = blockIdx.x;
    int r = removal_idx[ri];
    int* mark = g_mark1[ri];
    int* list = g_list1[ri];
    if (threadIdx.x == 0) claim(ri, r, mark, &g_n1[ri], list, CAP1);
    int s0 = g_rowO[r], s1 = g_rowO[r + 1];
    for (int i = s0 + threadIdx.x; i < s1; i += blockDim.x)
        claim(ri, g_csrO[i], mark, &g_n1[ri], list, CAP1);
}

// ---------------- recompute layer-1 for A1: grid (RR, CAP1), block 64 ----------------
__global__ void k_delta1(const int* __restrict__ removal_idx,
                         const float* __restrict__ Ws, const float* __restrict__ Wn,
                         const float* __restrict__ b) {
    int ri = blockIdx.x, j = blockIdx.y;
    if (j >= g_n1[ri]) return;
    int v = g_list1[ri][j];
    int r = removal_idx[ri];
    int d = threadIdx.x;

    float aggd = 0.f; int cnt = 0;
    if (v != r) {
        int s0 = g_rowI[v], s1 = g_rowI[v + 1];
        for (int i = s0; i < s1; i++) {
            int s = g_csrI[i];
            if (s == r) continue;
            aggd += g_h0[s * Df + d];
            cnt++;
        }
    }
    float aggn = aggd / fmaxf((float)cnt, 1.f);

    __shared__ float hv_s[Df], ag_s[Df];
    float hv = g_h0[v * Df + d];
    hv_s[d] = hv; ag_s[d] = aggn;
    __syncthreads();

    float acc = b[d];
#pragma unroll 16
    for (int k = 0; k < Df; k++)
        acc += hv_s[k] * Ws[k * Df + d] + ag_s[k] * Wn[k * Df + d];

    g_d1[ri][j][d] = fmaxf(acc, 0.f) + hv;
}

// ---------------- A2 = A1 ∪ out-neighbors(A1): grid (RR, CAP1), block 256 ----------------
__global__ void k_mark2(const int* __restrict__ removal_idx) {
    int ri = blockIdx.x, j = blockIdx.y;
    if (j >= g_n1[ri]) return;
    int u = g_list1[ri][j];
    int* mark = g_mark2[ri];
    int* list = g_list2[ri];
    if (threadIdx.x == 0) claim(ri, u, mark, &g_n2[ri], list, CAP2);
    int s0 = g_rowO[u], s1 = g_rowO[u + 1];
    for (int i = s0 + threadIdx.x; i < s1; i += blockDim.x)
        claim(ri, g_csrO[i], mark, &g_n2[ri], list, CAP2);
}

// ---------------- recompute layer-2 for A2: grid (RR, CAP2), block 64 ----------------
__global__ void k_delta2(const int* __restrict__ removal_idx,
                         const float* __restrict__ Ws, const float* __restrict__ Wn,
                         const float* __restrict__ b) {
    int ri = blockIdx.x, j = blockIdx.y;
    if (j >= g_n2[ri]) return;
    int v = g_list2[ri][j];
    int r = removal_idx[ri];
    int d = threadIdx.x;

    float aggd = 0.f; int cnt = 0;
    if (v != r) {
        int s0 = g_rowI[v], s1 = g_rowI[v + 1];
        for (int i = s0; i < s1; i++) {
            int s = g_csrI[i];
            if (s == r) continue;
            int m = g_mark1[ri][s];
            const float* hp = (m > 0) ? &g_d1[ri][m - 1][0] : &g_h1b[s * Df];
            aggd += hp[d];
            cnt++;
        }
    }
    float aggn = aggd / fmaxf((float)cnt, 1.f);

    __shared__ float hv_s[Df], ag_s[Df];
    int mv = g_mark1[ri][v];
    float hv = (mv > 0) ? g_d1[ri][mv - 1][d] : g_h1b[v * Df + d];
    hv_s[d] = hv; ag_s[d] = aggn;
    __syncthreads();

    float acc = b[d];
#pragma unroll 16
    for (int k = 0; k < Df; k++)
        acc += hv_s[k] * Ws[k * Df + d] + ag_s[k] * Wn[k * Df + d];

    g_d2[ri][j][d] = fmaxf(acc, 0.f) + hv;
}

// ---------------- edge scoring: grid (CC, RR), block 64 ----------------
__global__ void k_score(const int* __restrict__ conn, const int* __restrict__ removal_idx,
                        const int* __restrict__ esrc, const int* __restrict__ edst,
                        const float* __restrict__ We, const float* __restrict__ be,
                        const float* __restrict__ Wsc, const float* __restrict__ bsc) {
    int c = blockIdx.x, ri = blockIdx.y;
    int r = removal_idx[ri];
    int e = conn[ri * CC + c];
    int s = esrc[e], dd = edst[e];
    int j = threadIdx.x;

    int ms = g_mark2[ri][s], md = g_mark2[ri][dd];
    const float* hsp = (ms > 0) ? &g_d2[ri][ms - 1][0] : &g_h2b[s * Df];
    const float* hdp = (md > 0) ? &g_d2[ri][md - 1][0] : &g_h2b[dd * Df];

    __shared__ float hs[Df], hd[Df];
    hs[j] = hsp[j];
    hd[j] = hdp[j];
    __syncthreads();

    float acc = be[j];
#pragma unroll 16
    for (int k = 0; k < Df; k++)
        acc += hs[k] * We[k * Df + j] + hd[k] * We[(Df + k) * Df + j];
    float ef = fmaxf(acc, 0.f);

    float part = ef * Wsc[Df + j] + g_h0[r * Df + j] * Wsc[j];
#pragma unroll
    for (int off = 32; off > 0; off >>= 1) part += __shfl_xor(part, off);
    if (j == 0) g_score[ri * CC + c] = part + bsc[0];
}

// ---------------- softmax over C per removal ----------------
__global__ void k_softmax(float* __restrict__ out) {
    int r = blockIdx.x;
    int t = threadIdx.x;                        // 256 threads, 2 elems each
    float v0 = g_score[r * CC + t];
    float v1 = g_score[r * CC + 256 + t];
    __shared__ float red[256];
    red[t] = fmaxf(v0, v1);
    __syncthreads();
    for (int off = 128; off > 0; off >>= 1) {
        if (t < off) red[t] = fmaxf(red[t], red[t + off]);
        __syncthreads();
    }
    float mx = red[0];
    __syncthreads();
    float e0 = expf(v0 - mx), e1 = expf(v1 - mx);
    red[t] = e0 + e1;
    __syncthreads();
    for (int off = 128; off > 0; off >>= 1) {
        if (t < off) red[t] += red[t + off];
        __syncthreads();
    }
    float inv = 1.f / red[0];
    out[r * CC + t] = e0 * inv;
    out[r * CC + 256 + t] = e1 * inv;
}

extern "C" void kernel_launch(void* const* d_in, const int* in_sizes, int n_in,
                              void* d_out, int out_size, void* d_ws, size_t ws_size,
                              hipStream_t stream) {
    const float* coords   = (const float*)d_in[0];
    const float* W_emb    = (const float*)d_in[1];
    const float* b_emb    = (const float*)d_in[2];
    const float* W_self0  = (const float*)d_in[3];
    const float* W_neigh0 = (const float*)d_in[4];
    const float* b_gnn0   = (const float*)d_in[5];
    const float* W_self1  = (const float*)d_in[6];
    const float* W_neigh1 = (const float*)d_in[7];
    const float* b_gnn1   = (const float*)d_in[8];
    const float* W_edge   = (const float*)d_in[9];
    const float* b_edge   = (const float*)d_in[10];
    const float* W_score  = (const float*)d_in[11];
    const float* b_score  = (const float*)d_in[12];
    const int* esrc       = (const int*)d_in[13];
    const int* edst       = (const int*)d_in[14];
    const int* removal    = (const int*)d_in[15];
    const int* conn       = (const int*)d_in[16];

    k_zero<<<(RR * NN + 255) / 256, 256, 0, stream>>>();
    k_h0<<<(NN * Df + 255) / 256, 256, 0, stream>>>(coords, W_emb, b_emb);
    k_hist<<<(EE + 255) / 256, 256, 0, stream>>>(esrc, edst);
    k_scan<<<1, 1024, 0, stream>>>();
    k_fill<<<(EE + 255) / 256, 256, 0, stream>>>(esrc, edst);

    k_base<<<NN, 64, 0, stream>>>(0, W_self0, W_neigh0, b_gnn0);
    k_base<<<NN, 64, 0, stream>>>(1, W_self1, W_neigh1, b_gnn1);

    k_mark1<<<RR, 256, 0, stream>>>(removal);
    k_delta1<<<dim3(RR, CAP1), 64, 0, stream>>>(removal, W_self0, W_neigh0, b_gnn0);
    k_mark2<<<dim3(RR, CAP1), 256, 0, stream>>>(removal);
    k_delta2<<<dim3(RR, CAP2), 64, 0, stream>>>(removal, W_self1, W_neigh1, b_gnn1);

    k_score<<<dim3(CC, RR), 64, 0, stream>>>(conn, removal, esrc, edst,
                                             W_edge, b_edge, W_score, b_score);
    k_softmax<<<RR, 256, 0, stream>>>((float*)d_out);
}